// Round 2
// baseline (424.945 us; speedup 1.0000x reference)
//
#include <hip/hip_runtime.h>
#include <hip/hip_bf16.h>

// Problem constants (fixed by the reference):
//   B=128 graphs, N=64 nodes/graph, D=64 features, M=8192, HL=3, OL=2
//   adjacency is block-diagonal: only the 128 diagonal 64x64 blocks are
//   nonzero, and entries are exactly 0.0f or 1.0f.
// All float tensors are float32 (reference dtype); fingerprints int32.
#define MT   8192
#define DD   64
#define NPG  64
#define NB   128
#define BN_EPS 1e-5f

__device__ __forceinline__ float selu_f(float x) {
  const float scale = 1.0507009873554804934f;
  const float alpha = 1.6732632423543772848f;
  return x > 0.f ? scale * x : scale * alpha * (__expf(x) - 1.f);
}

// One block per graph. Computes y = x + A_b @ selu(x @ W^T + b), writes y to
// global, and atomically accumulates per-feature sum/sumsq for the batchnorm
// that the NEXT kernel applies on load.
// If stats_in == nullptr: layer 0 -> x comes from the embedding gather.
// Else: x = (xin - mu) * rsqrt(var + eps) computed from stats_in.
__global__ __launch_bounds__(256) void layer_k(
    const int* __restrict__ fpr,
    const float* __restrict__ emb,              // f32 [NFP, 64]
    const float* __restrict__ xin,              // f32 [M, 64] pre-norm (prev out)
    const float* __restrict__ stats_in,         // [128] = sum[64], sumsq[64]
    const float* __restrict__ adj,              // f32 [M, M], block-diagonal 0/1
    const float* __restrict__ Wf,               // f32 [64, 64] (this layer)
    const float* __restrict__ bfv,              // f32 [64]
    float* __restrict__ yout,                   // f32 [M, 64] pre-norm output
    float* __restrict__ stats_out)              // [128] accumulators (pre-zeroed)
{
  extern __shared__ char smem[];
  float* xs = (float*)smem;                          // 16384 B
  float* hs = (float*)(smem + 16384);                // 16384 B
  float* wT = (float*)(smem + 32768);                // 16384 B (dead after GEMM1)
  unsigned char* aU = (unsigned char*)(smem + 49152);// 4096 B (adj block as 0/1 bytes)
  float* mus = (float*)(smem + 53248);               // 256 B
  float* rss = (float*)(smem + 53504);               // 256 B -> total 53760 B
  // red1/red2 overlay wT after the GEMM1->GEMM2 barrier (needs 2048 floats)
  float* red1 = wT;
  float* red2 = wT + 1024;

  const int tid  = threadIdx.x;
  const int b    = blockIdx.x;
  const int tr   = tid >> 4;        // 0..15 (row group)
  const int tc   = tid & 15;        // 0..15 (col group)
  const int r0   = tr * 4;
  const int c0   = tc * 4;

  if (stats_in != nullptr && tid < DD) {
    float s1 = stats_in[tid];
    float s2 = stats_in[DD + tid];
    float mu = s1 * (1.f / MT);
    float var = fmaxf(s2 * (1.f / MT) - mu * mu, 0.f);
    mus[tid] = mu;
    rss[tid] = rsqrtf(var + BN_EPS);
  }

  // ---- stage adjacency block (as 0/1 bytes) and transposed weight ----
  for (int j = 0; j < 4; ++j) {
    int e = (tid + j * 256) * 4;                 // 0..4092, 4 elems/vec
    int n = e >> 6, k = e & 63;
    float4 av = *(const float4*)(adj + ((size_t)(b * NPG + n)) * MT + b * NPG + k);
    uchar4 u;
    u.x = (unsigned char)av.x; u.y = (unsigned char)av.y;
    u.z = (unsigned char)av.z; u.w = (unsigned char)av.w;
    *(uchar4*)(aU + e) = u;
    float4 wv = *(const float4*)(Wf + e);
    int d2 = e >> 6, k2 = e & 63;
    wT[(k2 + 0) * DD + d2] = wv.x;
    wT[(k2 + 1) * DD + d2] = wv.y;
    wT[(k2 + 2) * DD + d2] = wv.z;
    wT[(k2 + 3) * DD + d2] = wv.w;
  }
  __syncthreads();   // mus/rss + aU + wT ready

  // ---- stage x (embedding gather for layer 0, normalized prev-y otherwise) ----
  if (stats_in == nullptr) {
    for (int j = 0; j < 4; ++j) {
      int e = (tid + j * 256) * 4;
      int n = e >> 6, k = e & 63;
      int f = fpr[b * NPG + n];
      float4 v = *(const float4*)(emb + (size_t)f * DD + k);
      *(float4*)(xs + e) = v;
    }
  } else {
    const float* xg = xin + (size_t)b * NPG * DD;
    for (int j = 0; j < 4; ++j) {
      int e = (tid + j * 256) * 4;
      float4 v = *(const float4*)(xg + e);
      int d = e & 63;
      float4 o;
      o.x = (v.x - mus[d + 0]) * rss[d + 0];
      o.y = (v.y - mus[d + 1]) * rss[d + 1];
      o.z = (v.z - mus[d + 2]) * rss[d + 2];
      o.w = (v.w - mus[d + 3]) * rss[d + 3];
      *(float4*)(xs + e) = o;
    }
  }
  __syncthreads();

  // ---- GEMM1: h = selu(x @ W^T + b), 4x4 register tile per thread ----
  {
    float acc[4][4] = {};
    for (int k = 0; k < DD; k += 4) {
      float4 xv[4];
#pragma unroll
      for (int i = 0; i < 4; ++i) xv[i] = *(const float4*)(xs + (r0 + i) * DD + k);
#pragma unroll
      for (int kk = 0; kk < 4; ++kk) {
        float4 wv = *(const float4*)(wT + (k + kk) * DD + c0);
#pragma unroll
        for (int i = 0; i < 4; ++i) {
          float xk = ((const float*)&xv[i])[kk];
          acc[i][0] += xk * wv.x;
          acc[i][1] += xk * wv.y;
          acc[i][2] += xk * wv.z;
          acc[i][3] += xk * wv.w;
        }
      }
    }
    float b4[4];
#pragma unroll
    for (int c = 0; c < 4; ++c) b4[c] = bfv[c0 + c];
#pragma unroll
    for (int i = 0; i < 4; ++i) {
      float4 hv;
      hv.x = selu_f(acc[i][0] + b4[0]);
      hv.y = selu_f(acc[i][1] + b4[1]);
      hv.z = selu_f(acc[i][2] + b4[2]);
      hv.w = selu_f(acc[i][3] + b4[3]);
      *(float4*)(hs + (r0 + i) * DD + c0) = hv;
    }
  }
  __syncthreads();   // hs ready; wT dead from here (red1/red2 overlay)

  // ---- GEMM2: y = x + A @ h, stats accumulation ----
  {
    float acc[4][4] = {};
    for (int k = 0; k < DD; k += 4) {
      float a[4][4];
#pragma unroll
      for (int i = 0; i < 4; ++i) {
        uchar4 av = *(const uchar4*)(aU + (r0 + i) * DD + k);
        a[i][0] = (float)av.x; a[i][1] = (float)av.y;
        a[i][2] = (float)av.z; a[i][3] = (float)av.w;
      }
#pragma unroll
      for (int kk = 0; kk < 4; ++kk) {
        float4 hv = *(const float4*)(hs + (k + kk) * DD + c0);
#pragma unroll
        for (int i = 0; i < 4; ++i) {
          acc[i][0] += a[i][kk] * hv.x;
          acc[i][1] += a[i][kk] * hv.y;
          acc[i][2] += a[i][kk] * hv.z;
          acc[i][3] += a[i][kk] * hv.w;
        }
      }
    }
    float cs1[4] = {0.f, 0.f, 0.f, 0.f};
    float cs2[4] = {0.f, 0.f, 0.f, 0.f};
#pragma unroll
    for (int i = 0; i < 4; ++i) {
      float4 xv = *(const float4*)(xs + (r0 + i) * DD + c0);
      float y0 = acc[i][0] + xv.x;
      float y1 = acc[i][1] + xv.y;
      float y2 = acc[i][2] + xv.z;
      float y3 = acc[i][3] + xv.w;
      float4 yv = { y0, y1, y2, y3 };
      *(float4*)(yout + ((size_t)(b * NPG + r0 + i)) * DD + c0) = yv;
      cs1[0] += y0; cs2[0] += y0 * y0;
      cs1[1] += y1; cs2[1] += y1 * y1;
      cs1[2] += y2; cs2[2] += y2 * y2;
      cs1[3] += y3; cs2[3] += y3 * y3;
    }
#pragma unroll
    for (int c = 0; c < 4; ++c) {
      red1[tr * DD + c0 + c] = cs1[c];
      red2[tr * DD + c0 + c] = cs2[c];
    }
  }
  __syncthreads();
  if (tid < DD) {
    float t1 = 0.f, t2 = 0.f;
#pragma unroll
    for (int q = 0; q < 16; ++q) { t1 += red1[q * DD + tid]; t2 += red2[q * DD + tid]; }
    atomicAdd(&stats_out[tid], t1);
    atomicAdd(&stats_out[DD + tid], t2);
  }
}

// Normalize last layer output with its stats and mean-pool over the 64 nodes
// of each graph. One block (64 threads) per graph.
__global__ __launch_bounds__(64) void pool_k(const float* __restrict__ y,
                                             const float* __restrict__ stats,
                                             float* __restrict__ mol) {
  int b = blockIdx.x, d = threadIdx.x;
  float mu  = stats[d] * (1.f / MT);
  float var = fmaxf(stats[DD + d] * (1.f / MT) - mu * mu, 0.f);
  float rs  = rsqrtf(var + BN_EPS);
  const float* yb = y + (size_t)b * NPG * DD;
  float acc = 0.f;
#pragma unroll 8
  for (int n = 0; n < NPG; ++n) acc += yb[n * DD + d];
  mol[b * DD + d] = (acc * (1.f / NPG) - mu) * rs;   // mean is linear
}

// Whole output MLP head in one block: 2x (selu(mol @ Wo^T + bo) -> batchnorm
// over 128 rows), then mol @ Wp + bp -> f32 out[128].
__global__ __launch_bounds__(512) void final_k(
    const float* __restrict__ mol,
    const float* __restrict__ Wo,   // f32 [2,64,64]
    const float* __restrict__ bo,   // f32 [2,64]
    const float* __restrict__ Wp,   // f32 [64]
    const float* __restrict__ bp,   // f32 [1]
    float* __restrict__ out)        // f32 [128]
{
  __shared__ float t[128 * 65];       // padded: final dot reads row-wise
  __shared__ float wT[64 * 64];
  __shared__ float red1[8 * 64], red2[8 * 64];
  __shared__ float mus[64], rss[64];

  const int tid  = threadIdx.x;
  const int lane = tid & 63;
  const int w    = tid >> 6;          // 0..7

  for (int j = 0; j < 16; ++j) {
    int e = tid + j * 512;
    t[(e >> 6) * 65 + (e & 63)] = mol[e];
  }

  float acc[16];
  for (int layer = 0; layer < 2; ++layer) {
    __syncthreads();
    for (int j = 0; j < 8; ++j) {
      int e = tid + j * 512;
      wT[(e & 63) * 64 + (e >> 6)] = Wo[layer * 4096 + e];
    }
    float bias = bo[layer * 64 + lane];
    __syncthreads();
#pragma unroll
    for (int j = 0; j < 16; ++j) acc[j] = bias;
    for (int k = 0; k < 64; ++k) {
      float wv = wT[k * 64 + lane];
#pragma unroll
      for (int j = 0; j < 16; ++j)
        acc[j] += t[(w + 8 * j) * 65 + k] * wv;
    }
    float s1 = 0.f, s2 = 0.f;
#pragma unroll
    for (int j = 0; j < 16; ++j) {
      acc[j] = selu_f(acc[j]);
      s1 += acc[j]; s2 += acc[j] * acc[j];
    }
    red1[w * 64 + lane] = s1;
    red2[w * 64 + lane] = s2;
    __syncthreads();
    if (tid < 64) {
      float a1 = 0.f, a2 = 0.f;
#pragma unroll
      for (int q = 0; q < 8; ++q) { a1 += red1[q * 64 + tid]; a2 += red2[q * 64 + tid]; }
      float mu  = a1 * (1.f / 128);
      float var = fmaxf(a2 * (1.f / 128) - mu * mu, 0.f);
      mus[tid] = mu;
      rss[tid] = rsqrtf(var + BN_EPS);
    }
    __syncthreads();
#pragma unroll
    for (int j = 0; j < 16; ++j)
      t[(w + 8 * j) * 65 + lane] = (acc[j] - mus[lane]) * rss[lane];
  }
  __syncthreads();
  if (tid < 128) {
    float a = bp[0];
#pragma unroll
    for (int d = 0; d < 64; ++d) a += t[tid * 65 + d] * Wp[d];
    out[tid] = a;
  }
}

extern "C" void kernel_launch(void* const* d_in, const int* in_sizes, int n_in,
                              void* d_out, int out_size, void* d_ws, size_t ws_size,
                              hipStream_t stream) {
  (void)in_sizes; (void)n_in; (void)out_size; (void)ws_size;
  const int*   fpr = (const int*)d_in[0];
  const float* adj = (const float*)d_in[1];
  const float* emb = (const float*)d_in[2];
  const float* Wf  = (const float*)d_in[3];
  const float* bfv = (const float*)d_in[4];
  const float* Wo  = (const float*)d_in[5];
  const float* bo  = (const float*)d_in[6];
  const float* Wp  = (const float*)d_in[7];
  const float* bp  = (const float*)d_in[8];

  float* ws    = (float*)d_ws;
  float* bufA  = ws;                         // 524288 floats
  float* bufB  = ws + 524288;                // 524288 floats
  float* mol   = ws + 2 * 524288;            // 8192 floats
  float* stats = ws + 2 * 524288 + 8192;     // 384 floats (3 layers x [sum|sumsq])

  hipMemsetAsync(stats, 0, 384 * sizeof(float), stream);

  const size_t lds = 53760;  // xs+hs+wT+aU+mus/rss (red overlays wT)
  layer_k<<<NB, 256, lds, stream>>>(fpr, emb, nullptr, nullptr, adj,
                                    Wf + 0,    bfv + 0,   bufA, stats + 0);
  layer_k<<<NB, 256, lds, stream>>>(fpr, emb, bufA, stats + 0,   adj,
                                    Wf + 4096, bfv + 64,  bufB, stats + 128);
  layer_k<<<NB, 256, lds, stream>>>(fpr, emb, bufB, stats + 128, adj,
                                    Wf + 8192, bfv + 128, bufA, stats + 256);
  pool_k<<<NB, 64, 0, stream>>>(bufA, stats + 256, mol);
  final_k<<<1, 512, 0, stream>>>(mol, Wo, bo, Wp, bp, (float*)d_out);
}

// Round 3
// 389.411 us; speedup vs baseline: 1.0912x; 1.0912x over previous
//
#include <hip/hip_runtime.h>

// GNN, fixed shapes: B=128 graphs x N=64 nodes, D=64 features, M=8192, HL=3, OL=2.
// adjacency [8192x8192] f32 is block-diagonal (128 diagonal 64x64 blocks), entries
// exactly 0.0/1.0, and each block is SYMMETRIC (ref: max(blocks, swapaxes)).
// All float tensors f32; fingerprints int32.
//
// Strategy: ONE persistent kernel (128 blocks, trivially co-resident on 256 CUs)
// does embed-gather + 3 message-passing layers + pooling, with a device-scope
// atomic grid barrier at each BatchNorm (stats are batch-global). x stays in LDS
// the whole time (column-major, stride 68 to kill bank conflicts). A is read via
// symmetry so both GEMMs stream LDS conflict-free. A tiny 1-block kernel then
// runs the output MLP head.
#define MT   8192
#define DD   64
#define NPG  64
#define NB   128
#define XP   68          // padded column stride (floats) for xsc/wT
#define BN_EPS 1e-5f

__device__ __forceinline__ float selu_f(float x) {
  const float scale = 1.0507009873554804934f;
  const float alpha = 1.6732632423543772848f;
  return x > 0.f ? scale * x : scale * alpha * (__expf(x) - 1.f);
}

// Device-scope grid barrier (sense via generation counter). All 128 blocks are
// co-resident (128 blocks x 256 thr x ~56KB LDS on 256 CUs), so spin is safe.
__device__ __forceinline__ void gbar(int* cnt, int* gen) {
  __syncthreads();
  if (threadIdx.x == 0) {
    int g = __hip_atomic_load(gen, __ATOMIC_RELAXED, __HIP_MEMORY_SCOPE_AGENT);
    int a = __hip_atomic_fetch_add(cnt, 1, __ATOMIC_ACQ_REL, __HIP_MEMORY_SCOPE_AGENT);
    if (a == (int)gridDim.x - 1) {
      __hip_atomic_store(cnt, 0, __ATOMIC_RELAXED, __HIP_MEMORY_SCOPE_AGENT);
      __hip_atomic_store(gen, g + 1, __ATOMIC_RELEASE, __HIP_MEMORY_SCOPE_AGENT);
    } else {
      while (__hip_atomic_load(gen, __ATOMIC_ACQUIRE, __HIP_MEMORY_SCOPE_AGENT) == g)
        __builtin_amdgcn_s_sleep(1);
    }
  }
  __syncthreads();
}

__global__ __launch_bounds__(256) void gnn_k(
    const int* __restrict__ fpr,
    const float* __restrict__ emb,     // [NFP,64]
    const float* __restrict__ adj,     // [8192,8192] block-diagonal 0/1
    const float* __restrict__ Wf,      // [3,64,64]
    const float* __restrict__ bfv,     // [3,64]
    float* __restrict__ mol,           // out [128,64]
    float* __restrict__ stats,         // [3*128] zeroed (sum|sumsq per layer)
    int* __restrict__ bar)             // [2] zeroed (cnt, gen)
{
  __shared__ float xsc[XP * 64];          // x column-major: xsc[d*XP + n]
  __shared__ float wT[XP * 64];           // wT[k*XP + c] = W[c][k]; red overlays
  __shared__ float hs[64 * 64];           // h row-major: hs[n*64 + d]
  __shared__ unsigned char aU[64 * 64];   // A block bytes, aU[r*64 + k]
  __shared__ float mus[64], rss[64];
  float* red1 = wT;                       // overlay (wT dead between GEMM1s)
  float* red2 = wT + 1024;

  const int tid = threadIdx.x, b = blockIdx.x;
  const int tr = tid >> 4, tc = tid & 15;
  const int n0 = tr * 4, c0 = tc * 4;

  // ---- stage A block (bytes), W^T(layer0), x (embed gather, col-major) ----
  for (int j = 0; j < 4; ++j) {
    int e = (tid + j * 256) * 4;
    int r = e >> 6, k = e & 63;
    float4 av = *(const float4*)(adj + (size_t)(b * NPG + r) * MT + b * NPG + k);
    uchar4 u;
    u.x = (unsigned char)av.x; u.y = (unsigned char)av.y;
    u.z = (unsigned char)av.z; u.w = (unsigned char)av.w;
    *(uchar4*)(aU + e) = u;
    float4 wv = *(const float4*)(Wf + e);          // W[r][k..k+3]
    wT[(k + 0) * XP + r] = wv.x;
    wT[(k + 1) * XP + r] = wv.y;
    wT[(k + 2) * XP + r] = wv.z;
    wT[(k + 3) * XP + r] = wv.w;
    int f = fpr[b * NPG + r];
    float4 xv = *(const float4*)(emb + (size_t)f * DD + k);
    xsc[(k + 0) * XP + r] = xv.x;
    xsc[(k + 1) * XP + r] = xv.y;
    xsc[(k + 2) * XP + r] = xv.z;
    xsc[(k + 3) * XP + r] = xv.w;
  }
  __syncthreads();

  float poolp = 0.f;   // this thread's pooling partial (layer 2)

  for (int l = 0; l < 3; ++l) {
    // ---- GEMM1: h = selu(x @ W^T + b). xv: 4 rows at col d (conflict-free);
    //      wv: 4 out-features at k=d (conflict-free). ----
    {
      float acc[4][4] = {};
#pragma unroll 4
      for (int d = 0; d < DD; ++d) {
        float4 xv = *(const float4*)(xsc + d * XP + n0);
        float4 wv = *(const float4*)(wT + d * XP + c0);
#pragma unroll
        for (int i = 0; i < 4; ++i) {
          float xk = ((const float*)&xv)[i];
          acc[i][0] += xk * wv.x;
          acc[i][1] += xk * wv.y;
          acc[i][2] += xk * wv.z;
          acc[i][3] += xk * wv.w;
        }
      }
      float b4[4];
#pragma unroll
      for (int c = 0; c < 4; ++c) b4[c] = bfv[l * DD + c0 + c];
#pragma unroll
      for (int i = 0; i < 4; ++i) {
        float4 hv;
        hv.x = selu_f(acc[i][0] + b4[0]);
        hv.y = selu_f(acc[i][1] + b4[1]);
        hv.z = selu_f(acc[i][2] + b4[2]);
        hv.w = selu_f(acc[i][3] + b4[3]);
        *(float4*)(hs + (n0 + i) * DD + c0) = hv;
      }
    }
    __syncthreads();   // hs ready; wT dead -> red1/red2 usable

    // ---- GEMM2: y = x + A @ h. A read via symmetry: aU[k*64+n] = A[n][k];
    //      uchar4 over n (distinct banks), hv over cols (conflict-free). ----
    {
      float acc[4][4] = {};
#pragma unroll 4
      for (int k = 0; k < DD; ++k) {
        uchar4 a4 = *(const uchar4*)(aU + k * DD + n0);
        float4 hv = *(const float4*)(hs + k * DD + c0);
        float af[4] = { (float)a4.x, (float)a4.y, (float)a4.z, (float)a4.w };
#pragma unroll
        for (int i = 0; i < 4; ++i) {
          acc[i][0] += af[i] * hv.x;
          acc[i][1] += af[i] * hv.y;
          acc[i][2] += af[i] * hv.z;
          acc[i][3] += af[i] * hv.w;
        }
      }
      // residual + in-place update of xsc (own cells only) + column stats
#pragma unroll
      for (int c = 0; c < 4; ++c) {
        float* p = xsc + (c0 + c) * XP + n0;
        float4 xo = *(const float4*)p;
        float y0 = acc[0][c] + xo.x;
        float y1 = acc[1][c] + xo.y;
        float y2 = acc[2][c] + xo.z;
        float y3 = acc[3][c] + xo.w;
        float4 yv = { y0, y1, y2, y3 };
        *(float4*)p = yv;
        red1[tr * DD + c0 + c] = y0 + y1 + y2 + y3;
        red2[tr * DD + c0 + c] = y0 * y0 + y1 * y1 + y2 * y2 + y3 * y3;
      }
    }
    __syncthreads();
    if (tid < DD) {
      float t1 = 0.f, t2 = 0.f;
#pragma unroll
      for (int q = 0; q < 16; ++q) { t1 += red1[q * DD + tid]; t2 += red2[q * DD + tid]; }
      atomicAdd(&stats[l * 128 + tid], t1);
      atomicAdd(&stats[l * 128 + DD + tid], t2);
    }

    gbar(bar, bar + 1);   // batch-global BN stats complete

    if (tid < DD) {
      float s1 = __hip_atomic_load(&stats[l * 128 + tid], __ATOMIC_RELAXED,
                                   __HIP_MEMORY_SCOPE_AGENT);
      float s2 = __hip_atomic_load(&stats[l * 128 + DD + tid], __ATOMIC_RELAXED,
                                   __HIP_MEMORY_SCOPE_AGENT);
      float mu  = s1 * (1.f / MT);
      float var = fmaxf(s2 * (1.f / MT) - mu * mu, 0.f);
      mus[tid] = mu;
      rss[tid] = rsqrtf(var + BN_EPS);
    }
    __syncthreads();

    // ---- normalize xsc in place; thread owns column d = tid>>2, quarter q ----
    {
      int d = tid >> 2, q = tid & 3;
      float mu = mus[d], rs = rss[d];
      float* p = xsc + d * XP + q * 16;
      float ps = 0.f;
#pragma unroll
      for (int w = 0; w < 4; ++w) {
        float4 v = *(const float4*)(p + w * 4);
        v.x = (v.x - mu) * rs; v.y = (v.y - mu) * rs;
        v.z = (v.z - mu) * rs; v.w = (v.w - mu) * rs;
        *(float4*)(p + w * 4) = v;
        ps += v.x + v.y + v.z + v.w;
      }
      poolp = ps;
    }
    if (l < 2) {
      // restage wT for next layer (red1/red2 already consumed)
      for (int j = 0; j < 4; ++j) {
        int e = (tid + j * 256) * 4;
        int r = e >> 6, k = e & 63;
        float4 wv = *(const float4*)(Wf + (size_t)(l + 1) * 4096 + e);
        wT[(k + 0) * XP + r] = wv.x;
        wT[(k + 1) * XP + r] = wv.y;
        wT[(k + 2) * XP + r] = wv.z;
        wT[(k + 3) * XP + r] = wv.w;
      }
    } else {
      red1[tid] = poolp;   // pooling partials (wT region free on last layer)
    }
    __syncthreads();
  }

  // ---- pool: mean over the 64 nodes of this graph (values already normalized)
  if (tid < DD) {
    float s = red1[tid * 4] + red1[tid * 4 + 1] + red1[tid * 4 + 2] + red1[tid * 4 + 3];
    mol[b * DD + tid] = s * (1.f / NPG);
  }
}

// Whole output MLP head in one block: 2x (selu(mol @ Wo^T + bo) -> batchnorm
// over 128 rows), then mol @ Wp + bp -> f32 out[128].
__global__ __launch_bounds__(512) void final_k(
    const float* __restrict__ mol,
    const float* __restrict__ Wo,   // f32 [2,64,64]
    const float* __restrict__ bo,   // f32 [2,64]
    const float* __restrict__ Wp,   // f32 [64]
    const float* __restrict__ bp,   // f32 [1]
    float* __restrict__ out)        // f32 [128]
{
  __shared__ float t[128 * 65];
  __shared__ float wT[64 * 64];
  __shared__ float red1[8 * 64], red2[8 * 64];
  __shared__ float mus[64], rss[64];

  const int tid  = threadIdx.x;
  const int lane = tid & 63;
  const int w    = tid >> 6;          // 0..7

  for (int j = 0; j < 16; ++j) {
    int e = tid + j * 512;
    t[(e >> 6) * 65 + (e & 63)] = mol[e];
  }

  float acc[16];
  for (int layer = 0; layer < 2; ++layer) {
    __syncthreads();
    for (int j = 0; j < 8; ++j) {
      int e = tid + j * 512;
      wT[(e & 63) * 64 + (e >> 6)] = Wo[layer * 4096 + e];
    }
    float bias = bo[layer * 64 + lane];
    __syncthreads();
#pragma unroll
    for (int j = 0; j < 16; ++j) acc[j] = bias;
    for (int k = 0; k < 64; ++k) {
      float wv = wT[k * 64 + lane];
#pragma unroll
      for (int j = 0; j < 16; ++j)
        acc[j] += t[(w + 8 * j) * 65 + k] * wv;
    }
    float s1 = 0.f, s2 = 0.f;
#pragma unroll
    for (int j = 0; j < 16; ++j) {
      acc[j] = selu_f(acc[j]);
      s1 += acc[j]; s2 += acc[j] * acc[j];
    }
    red1[w * 64 + lane] = s1;
    red2[w * 64 + lane] = s2;
    __syncthreads();
    if (tid < 64) {
      float a1 = 0.f, a2 = 0.f;
#pragma unroll
      for (int q = 0; q < 8; ++q) { a1 += red1[q * 64 + tid]; a2 += red2[q * 64 + tid]; }
      float mu  = a1 * (1.f / 128);
      float var = fmaxf(a2 * (1.f / 128) - mu * mu, 0.f);
      mus[tid] = mu;
      rss[tid] = rsqrtf(var + BN_EPS);
    }
    __syncthreads();
#pragma unroll
    for (int j = 0; j < 16; ++j)
      t[(w + 8 * j) * 65 + lane] = (acc[j] - mus[lane]) * rss[lane];
  }
  __syncthreads();
  if (tid < 128) {
    float a = bp[0];
#pragma unroll
    for (int d = 0; d < 64; ++d) a += t[tid * 65 + d] * Wp[d];
    out[tid] = a;
  }
}

extern "C" void kernel_launch(void* const* d_in, const int* in_sizes, int n_in,
                              void* d_out, int out_size, void* d_ws, size_t ws_size,
                              hipStream_t stream) {
  (void)in_sizes; (void)n_in; (void)out_size; (void)ws_size;
  const int*   fpr = (const int*)d_in[0];
  const float* adj = (const float*)d_in[1];
  const float* emb = (const float*)d_in[2];
  const float* Wf  = (const float*)d_in[3];
  const float* bfv = (const float*)d_in[4];
  const float* Wo  = (const float*)d_in[5];
  const float* bo  = (const float*)d_in[6];
  const float* Wp  = (const float*)d_in[7];
  const float* bp  = (const float*)d_in[8];

  float* ws    = (float*)d_ws;
  float* stats = ws;                 // 384 floats (3 layers x [sum|sumsq])
  int*   bar   = (int*)(ws + 384);   // 2 ints (cnt, gen)
  float* mol   = ws + 512;           // 8192 floats

  hipMemsetAsync(ws, 0, (384 + 2) * sizeof(float), stream);

  gnn_k<<<NB, 256, 0, stream>>>(fpr, emb, adj, Wf, bfv, mol, stats, bar);
  final_k<<<1, 512, 0, stream>>>(mol, Wo, bo, Wp, bp, (float*)d_out);
}